// Round 1
// baseline (2167.157 us; speedup 1.0000x reference)
//
#include <hip/hip_runtime.h>
#include <hip/hip_bf16.h>

#define UNIT 20
#define HID 36
#define G4 144      // 4*HID
#define INW 80      // 4*UNIT
#define NCLS 3
#define TT 40960
#define SS 2048     // TT/UNIT
#define CH 16       // chunk of timesteps
#define NCHUNK (SS/CH)

__device__ __forceinline__ float exp2_hw(float x){ float r; asm("v_exp_f32 %0, %1" : "=v"(r) : "v"(x)); return r; }
__device__ __forceinline__ float rcp_hw(float x){ float r; asm("v_rcp_f32 %0, %1" : "=v"(r) : "v"(x)); return r; }

__global__ __launch_bounds__(192)
void lstm_fused(const float* __restrict__ x, const float* __restrict__ h0,
                const float* __restrict__ c0, const float* __restrict__ W_ih,
                const float* __restrict__ W_hh, const float* __restrict__ b_ih,
                const float* __restrict__ b_hh, const float* __restrict__ fc1_w,
                const float* __restrict__ fc1_b, const float* __restrict__ fc2_w,
                const float* __restrict__ fc2_b, float* __restrict__ out)
{
    const int b = blockIdx.x;
    const int t = threadIdx.x;

    __shared__ __align__(16) float xin[CH][INW];   // 5 KB
    __shared__ __align__(16) float xw[CH][G4];     // 9 KB
    __shared__ __align__(16) float h_s[HID];
    __shared__ __align__(16) float g_s[G4];

    // per-thread weights in registers (threads 0..143)
    float wih[INW];
    float whh[HID];
    float bias = 0.f, K = 0.f, Aa = 0.f, Bb = 0.f;
    if (t < G4) {
        const float4* wr = (const float4*)(W_ih + t * INW);   // 320B rows, 16B aligned
        #pragma unroll
        for (int i = 0; i < INW/4; ++i) {
            float4 v = wr[i];
            wih[4*i+0] = v.x; wih[4*i+1] = v.y; wih[4*i+2] = v.z; wih[4*i+3] = v.w;
        }
        const float4* hr = (const float4*)(W_hh + t * HID);   // 144B rows, 16B aligned
        #pragma unroll
        for (int j = 0; j < HID/4; ++j) {
            float4 v = hr[j];
            whh[4*j+0] = v.x; whh[4*j+1] = v.y; whh[4*j+2] = v.z; whh[4*j+3] = v.w;
        }
        bias = b_ih[t] + b_hh[t];
        // gates order: i[0:36] f[36:72] g[72:108] o[108:144]
        // sigmoid(x) = rcp(1 + exp2(-x*log2e))         -> K=-log2e, A=0, B=1
        // tanh(x)    = 1 - 2*rcp(1 + exp2(2x*log2e))   -> K=2log2e, A=1, B=-2
        const bool tnh = (t >= 2*HID && t < 3*HID);
        K  = tnh ?  2.8853900817779268f : -1.4426950408889634f;
        Aa = tnh ?  1.f : 0.f;
        Bb = tnh ? -2.f : 1.f;
    }
    float c = 0.f;
    if (t < HID) { c = c0[b*HID + t]; h_s[t] = h0[b*HID + t]; }
    __syncthreads();

    const float* xb = x + (size_t)b * 4 * TT;

    for (int ck = 0; ck < NCHUNK; ++ck) {
        // ---- load x chunk (coalesced: 4 channels x 320 contiguous floats) ----
        const int base = ck * CH * UNIT;
        for (int j = t; j < 4*CH*UNIT; j += 192) {
            int chn = j / (CH*UNIT);
            int r   = j - chn * (CH*UNIT);     // s*20 + u
            int s   = r / UNIT;
            int u   = r - s * UNIT;
            xin[s][chn*UNIT + u] = xb[chn*TT + base + r];
        }
        __syncthreads();

        // ---- input projection for the chunk ----
        if (t < G4) {
            for (int s = 0; s < CH; ++s) {
                const float4* xv = (const float4*)xin[s];
                float a0 = bias, a1 = 0.f, a2 = 0.f, a3 = 0.f;
                #pragma unroll
                for (int i = 0; i < INW/4; ++i) {
                    float4 v = xv[i];
                    a0 += v.x * wih[4*i+0];
                    a1 += v.y * wih[4*i+1];
                    a2 += v.z * wih[4*i+2];
                    a3 += v.w * wih[4*i+3];
                }
                xw[s][t] = (a0 + a1) + (a2 + a3);
            }
        }
        __syncthreads();

        // ---- recurrence over the chunk ----
        for (int s = 0; s < CH; ++s) {
            if (t < G4) {
                const float4* hv = (const float4*)h_s;
                float a0 = xw[s][t], a1 = 0.f, a2 = 0.f, a3 = 0.f;
                #pragma unroll
                for (int j = 0; j < HID/4; ++j) {
                    float4 v = hv[j];
                    a0 += v.x * whh[4*j+0];
                    a1 += v.y * whh[4*j+1];
                    a2 += v.z * whh[4*j+2];
                    a3 += v.w * whh[4*j+3];
                }
                float acc = (a0 + a1) + (a2 + a3);
                float e = exp2_hw(K * acc);
                g_s[t] = Aa + Bb * rcp_hw(1.f + e);
            }
            __syncthreads();
            if (t < HID) {
                float ig = g_s[t], fg = g_s[HID+t], gg = g_s[2*HID+t], og = g_s[3*HID+t];
                c = fg * c + ig * gg;
                float e = exp2_hw(2.8853900817779268f * c);
                float th = 1.f - 2.f * rcp_hw(1.f + e);
                h_s[t] = og * th;
            }
            __syncthreads();
        }
    }

    // ---- classifier head ----
    if (t < 16) {
        float acc = fc1_b[t];
        #pragma unroll
        for (int j = 0; j < HID; ++j) acc += h_s[j] * fc1_w[t*HID + j];
        g_s[t] = fmaxf(acc, 0.f);
    }
    __syncthreads();
    if (t < NCLS) {
        float acc = fc2_b[t];
        #pragma unroll
        for (int j = 0; j < 16; ++j) acc += g_s[j] * fc2_w[t*16 + j];
        out[b*NCLS + t] = acc;
    }
}

extern "C" void kernel_launch(void* const* d_in, const int* in_sizes, int n_in,
                              void* d_out, int out_size, void* d_ws, size_t ws_size,
                              hipStream_t stream) {
    const float* x     = (const float*)d_in[0];
    const float* h0    = (const float*)d_in[1];
    const float* c0    = (const float*)d_in[2];
    const float* W_ih  = (const float*)d_in[3];
    const float* W_hh  = (const float*)d_in[4];
    const float* b_ih  = (const float*)d_in[5];
    const float* b_hh  = (const float*)d_in[6];
    const float* fc1_w = (const float*)d_in[7];
    const float* fc1_b = (const float*)d_in[8];
    const float* fc2_w = (const float*)d_in[9];
    const float* fc2_b = (const float*)d_in[10];
    float* out = (float*)d_out;

    lstm_fused<<<512, 192, 0, stream>>>(x, h0, c0, W_ih, W_hh, b_ih, b_hh,
                                        fc1_w, fc1_b, fc2_w, fc2_b, out);
}